// Round 2
// baseline (941.186 us; speedup 1.0000x reference)
//
#include <hip/hip_runtime.h>
#include <hip/hip_bf16.h>
#include <math.h>

#define N_NODES 4096
#define N_EDGES 131072
#define DIN 148
#define DHID 128
#define DOUT 148

// ---------------- dedup edges into bitmap + unique list + degrees ----------------
// NOTE: harness converts int64 inputs to int32 -> read as const int*.
__global__ __launch_bounds__(256) void dedup_kernel(const int* __restrict__ ei,
                                                    unsigned* __restrict__ bitmap,
                                                    unsigned* __restrict__ nuniq,
                                                    unsigned* __restrict__ uniq,
                                                    int* __restrict__ rowdeg,
                                                    int* __restrict__ coldeg) {
    int k = blockIdx.x * 256 + threadIdx.x;           // exactly N_EDGES threads
    int i = ei[k] & (N_NODES - 1);
    int j = ei[k + N_EDGES] & (N_NODES - 1);
    unsigned pos = (unsigned)i * (unsigned)N_NODES + (unsigned)j;
    unsigned w = pos >> 5, m = 1u << (pos & 31u);
    unsigned old = atomicOr(&bitmap[w], m);
    if (!(old & m)) {
        unsigned u = atomicAdd(nuniq, 1u);
        uniq[u] = ((unsigned)i << 12) | (unsigned)j;
        atomicAdd(&rowdeg[i], 1);
        atomicAdd(&coldeg[j], 1);
    }
}

// ---------------- prefix scan of row degrees + normalization coefs ----------------
__global__ __launch_bounds__(1024) void scan_kernel(const int* __restrict__ rowdeg,
                                                    const int* __restrict__ coldeg,
                                                    int* __restrict__ row_ofs,
                                                    float* __restrict__ rs,
                                                    float* __restrict__ acoef,
                                                    const float* __restrict__ a_param) {
    __shared__ int sh[1024];
    int t = threadIdx.x;
    int base = t * 4;
    int v0 = rowdeg[base], v1 = rowdeg[base+1], v2 = rowdeg[base+2], v3 = rowdeg[base+3];
    int p = v0 + v1 + v2 + v3;
    sh[t] = p;
    __syncthreads();
    for (int off = 1; off < 1024; off <<= 1) {
        int x = (t >= off) ? sh[t - off] : 0;
        __syncthreads();
        sh[t] += x;
        __syncthreads();
    }
    int excl = sh[t] - p;
    row_ofs[base]     = excl;
    row_ofs[base + 1] = excl + v0;
    row_ofs[base + 2] = excl + v0 + v1;
    row_ofs[base + 3] = excl + v0 + v1 + v2;
    if (t == 1023) row_ofs[N_NODES] = sh[1023];

    float alpha = 0.5f + 0.5f * tanhf(2.0f * a_param[0]);
    for (int r = 0; r < 4; ++r) {
        int i = base + r;
        int rd = rowdeg[i], cd = coldeg[i];
        rs[i]    = (rd > 0) ? rsqrtf((float)rd) : 0.0f;           // R_is[j] (row sums)
        acoef[i] = (cd > 0) ? alpha * rsqrtf((float)cd) : 0.0f;   // alpha * L_is[i] (col sums)
    }
}

// ---------------- fill CSR (col + per-edge coefficient) ----------------
__global__ __launch_bounds__(256) void fill_kernel(const unsigned* __restrict__ uniq,
                                                   const unsigned* __restrict__ nuniq,
                                                   const int* __restrict__ row_ofs,
                                                   int* __restrict__ cursor,
                                                   const float* __restrict__ rs,
                                                   uint2* __restrict__ colcoef) {
    int t = blockIdx.x * 256 + threadIdx.x;
    if (t >= (int)(*nuniq)) return;
    unsigned p = uniq[t];
    int i = (int)(p >> 12);
    int j = (int)(p & 4095u);
    int pos = atomicAdd(&cursor[i], 1);
    colcoef[row_ofs[i] + pos] = make_uint2((unsigned)j, __float_as_uint(rs[j]));
}

// ---------------- weight transposes for coalesced GEMV ----------------
__global__ __launch_bounds__(256) void transpose_kernel(const float* __restrict__ W1,
                                                        const float* __restrict__ Wd,
                                                        float* __restrict__ W1T,
                                                        float* __restrict__ WdT) {
    const int S = DIN * DHID; // 18944
    int id = blockIdx.x * 256 + threadIdx.x;
    if (id < S) {
        int k = id >> 7, d = id & 127;
        W1T[id] = W1[d * DIN + k];          // W1T[k*128 + d]
    } else if (id < 2 * S) {
        int id2 = id - S;
        int h = id2 / DOUT, o = id2 - h * DOUT;
        WdT[id2] = Wd[o * DHID + h];        // WdT[h*148 + o]
    }
}

// ---------------- linear1: B = node_feat @ W1.T + b1 ----------------
__global__ __launch_bounds__(128) void linear1_kernel(const float* __restrict__ nf,
                                                      const float* __restrict__ W1T,
                                                      const float* __restrict__ b1,
                                                      float* __restrict__ B) {
    __shared__ float s[DIN];
    int i = blockIdx.x, d = threadIdx.x;
    s[d] = nf[i * DIN + d];
    if (d + 128 < DIN) s[d + 128] = nf[i * DIN + d + 128];
    __syncthreads();
    float acc = b1[d];
    for (int k = 0; k < DIN; ++k) acc += s[k] * W1T[k * DHID + d];
    B[i * DHID + d] = acc;
}

// ---------------- one Richardson iteration: xout = B + acoef[r] * sum_j rs[j]*xin[j] ----------------
__global__ __launch_bounds__(256) void spmv_kernel(const float* __restrict__ xin,
                                                   float* __restrict__ xout,
                                                   const float* __restrict__ B,
                                                   const uint2* __restrict__ colcoef,
                                                   const int* __restrict__ row_ofs,
                                                   const float* __restrict__ acoef) {
    int r = blockIdx.x * 2 + (threadIdx.x >> 7);
    int d = threadIdx.x & 127;
    int s = row_ofs[r], e = row_ofs[r + 1];
    float a0 = 0.0f, a1 = 0.0f;
    int t = s;
    for (; t + 1 < e; t += 2) {
        uint2 c0 = colcoef[t];
        uint2 c1 = colcoef[t + 1];
        a0 += __uint_as_float(c0.y) * xin[(int)c0.x * DHID + d];
        a1 += __uint_as_float(c1.y) * xin[(int)c1.x * DHID + d];
    }
    if (t < e) {
        uint2 c0 = colcoef[t];
        a0 += __uint_as_float(c0.y) * xin[(int)c0.x * DHID + d];
    }
    int idx = r * DHID + d;
    xout[idx] = B[idx] + acoef[r] * (a0 + a1);
}

// ---------------- dots for extrapolation: out[0]+=dp.dp  out[1]+=dn.dp ----------------
__global__ __launch_bounds__(256) void dots_kernel(const float* __restrict__ last,
                                                   const float* __restrict__ prev,
                                                   const float* __restrict__ prev2,
                                                   double* __restrict__ out) {
    const int n = N_NODES * DHID;
    double s0 = 0.0, s1 = 0.0;
    for (int idx = blockIdx.x * 256 + threadIdx.x; idx < n; idx += gridDim.x * 256) {
        float dp = prev[idx] - prev2[idx];
        float dn = last[idx] - prev[idx];
        s0 += (double)dp * (double)dp;
        s1 += (double)dn * (double)dp;
    }
    __shared__ double sh0[256], sh1[256];
    int t = threadIdx.x;
    sh0[t] = s0; sh1[t] = s1;
    __syncthreads();
    for (int off = 128; off > 0; off >>= 1) {
        if (t < off) { sh0[t] += sh0[t + off]; sh1[t] += sh1[t + off]; }
        __syncthreads();
    }
    if (t == 0) {
        atomicAdd(&out[0], sh0[0]);
        atomicAdd(&out[1], sh1[0]);
    }
}

// ---------------- extrapolation: out = last + s*(last-prev), s = lam/(1-lam) ----------------
__global__ __launch_bounds__(256) void extrap_kernel(const float* __restrict__ last,
                                                     const float* __restrict__ prev,
                                                     const double* __restrict__ dots,
                                                     float* __restrict__ xo) {
    double d0 = dots[0], d1 = dots[1];
    float lam = (d0 > 0.0) ? (float)(d1 / d0) : 0.0f;
    float den = 1.0f - lam;
    if (fabsf(den) < 1e-4f) den = (den < 0.0f) ? -1e-4f : 1e-4f;
    float s = lam / den;
    s = fminf(fmaxf(s, -1e4f), 1e4f);
    const int n = N_NODES * DHID;
    for (int idx = blockIdx.x * 256 + threadIdx.x; idx < n; idx += gridDim.x * 256) {
        float l = last[idx];
        xo[idx] = l + s * (l - prev[idx]);
    }
}

// ---------------- linear_d: yD = x @ Wd.T + bd ----------------
__global__ __launch_bounds__(192) void lineard_kernel(const float* __restrict__ x,
                                                      const float* __restrict__ WdT,
                                                      const float* __restrict__ bd,
                                                      float* __restrict__ yD) {
    __shared__ float s[DHID];
    int i = blockIdx.x, o = threadIdx.x;
    if (o < DHID) s[o] = x[i * DHID + o];
    __syncthreads();
    if (o < DOUT) {
        float acc = bd[o];
        for (int h = 0; h < DHID; ++h) acc += s[h] * WdT[h * DOUT + o];
        yD[i * DOUT + o] = acc;
    }
}

// ---------------- sim loss: sum over i!=j of relu(yD_i . yD_j / sqrt(128)) ----------------
#define TS 64
#define KC 74
#define KSTR 77
__global__ __launch_bounds__(256) void simloss_kernel(const float* __restrict__ yD,
                                                      double* __restrict__ acc) {
    int bj = blockIdx.x, bi = blockIdx.y;
    if (bi > bj) return;
    __shared__ float As[TS][KSTR];
    __shared__ float Bs[TS][KSTR];
    int tid = threadIdx.x;
    int ty = tid >> 4, tx = tid & 15;
    float av[4][4];
#pragma unroll
    for (int r = 0; r < 4; ++r)
#pragma unroll
        for (int c = 0; c < 4; ++c) av[r][c] = 0.0f;

    for (int kc = 0; kc < 2; ++kc) {
        for (int idx = tid; idx < TS * KC; idx += 256) {
            int rr = idx / KC, cc = idx - rr * KC;
            As[rr][cc] = yD[(bi * TS + rr) * DOUT + kc * KC + cc];
            Bs[rr][cc] = yD[(bj * TS + rr) * DOUT + kc * KC + cc];
        }
        __syncthreads();
        for (int k = 0; k < KC; ++k) {
            float a0 = As[ty*4+0][k], a1 = As[ty*4+1][k], a2 = As[ty*4+2][k], a3 = As[ty*4+3][k];
            float b0 = Bs[tx*4+0][k], b1 = Bs[tx*4+1][k], b2 = Bs[tx*4+2][k], b3 = Bs[tx*4+3][k];
            av[0][0]+=a0*b0; av[0][1]+=a0*b1; av[0][2]+=a0*b2; av[0][3]+=a0*b3;
            av[1][0]+=a1*b0; av[1][1]+=a1*b1; av[1][2]+=a1*b2; av[1][3]+=a1*b3;
            av[2][0]+=a2*b0; av[2][1]+=a2*b1; av[2][2]+=a2*b2; av[2][3]+=a2*b3;
            av[3][0]+=a3*b0; av[3][1]+=a3*b1; av[3][2]+=a3*b2; av[3][3]+=a3*b3;
        }
        __syncthreads();
    }
    const float inv = 0.0883883476483184405f; // 1/sqrt(128)
    float wgt = (bi == bj) ? 1.0f : 2.0f;
    float lsum = 0.0f;
#pragma unroll
    for (int r = 0; r < 4; ++r)
#pragma unroll
        for (int c = 0; c < 4; ++c) {
            int gi = bi * TS + ty * 4 + r;
            int gj = bj * TS + tx * 4 + c;
            float v = av[r][c] * inv;
            if (gi != gj && v > 0.0f) lsum += wgt * v;
        }
    for (int o2 = 32; o2 > 0; o2 >>= 1) lsum += __shfl_down(lsum, o2);
    __shared__ float wsum[4];
    if ((tid & 63) == 0) wsum[tid >> 6] = lsum;
    __syncthreads();
    if (tid == 0) atomicAdd(acc, (double)(wsum[0] + wsum[1] + wsum[2] + wsum[3]));
}

// ---------------- column max over nodes ----------------
__global__ __launch_bounds__(256) void pool_kernel(const float* __restrict__ yD,
                                                   float* __restrict__ m) {
    int o = blockIdx.x;
    int tid = threadIdx.x;
    float mx = -3.4e38f;
    for (int i = tid; i < N_NODES; i += 256) mx = fmaxf(mx, yD[i * DOUT + o]);
    for (int off = 32; off > 0; off >>= 1) mx = fmaxf(mx, __shfl_down(mx, off));
    __shared__ float sm[4];
    if ((tid & 63) == 0) sm[tid >> 6] = mx;
    __syncthreads();
    if (tid == 0) m[o] = fmaxf(fmaxf(sm[0], sm[1]), fmaxf(sm[2], sm[3]));
}

// ---------------- final outputs ----------------
__global__ __launch_bounds__(64) void final_kernel(const float* __restrict__ m,
                                                   const float* __restrict__ W2,
                                                   const float* __restrict__ b2,
                                                   const double* __restrict__ acc,
                                                   const float* __restrict__ a_param,
                                                   float* __restrict__ out) {
    int l = threadIdx.x;
    float alpha = 0.5f + 0.5f * tanhf(2.0f * a_param[0]);
    float oma = 1.0f - alpha;
    float s0 = 0.0f, s1 = 0.0f;
    for (int o = l; o < DOUT; o += 64) {
        float p = fmaxf(m[o], 0.0f);
        s0 += p * W2[o];
        s1 += p * W2[DOUT + o];
    }
    for (int off = 32; off > 0; off >>= 1) {
        s0 += __shfl_down(s0, off);
        s1 += __shfl_down(s1, off);
    }
    if (l == 0) {
        out[0] = b2[0] + oma * s0;
        out[1] = b2[1] + oma * s1;
        out[2] = (float)(acc[0] / (4096.0 * 4095.0));
    }
}

extern "C" void kernel_launch(void* const* d_in, const int* in_sizes, int n_in,
                              void* d_out, int out_size, void* d_ws, size_t ws_size,
                              hipStream_t stream) {
    (void)in_sizes; (void)n_in; (void)out_size; (void)ws_size;
    const float* node_feat  = (const float*)d_in[0];
    const int*   edge_index = (const int*)d_in[1];   // harness converts int64 -> int32
    const float* W1         = (const float*)d_in[3];
    const float* b1         = (const float*)d_in[4];
    const float* a_param    = (const float*)d_in[5];
    const float* Wd         = (const float*)d_in[6];
    const float* bd         = (const float*)d_in[7];
    const float* W2         = (const float*)d_in[8];
    const float* b2         = (const float*)d_in[9];
    float*       out        = (float*)d_out;

    char* w = (char*)d_ws;
    size_t off = 0;
    auto alloc = [&](size_t bytes) -> char* {
        char* p = w + off;
        off = (off + bytes + 255) & ~(size_t)255;
        return p;
    };
    double*   acc     = (double*)   alloc(8 * sizeof(double));   // [0]=loss, [1,2]=ph1 dots, [3,4]=ph2 dots
    unsigned* cnt     = (unsigned*) alloc(16 * sizeof(unsigned));
    int*      rowdeg  = (int*)      alloc(N_NODES * 4);
    int*      coldeg  = (int*)      alloc(N_NODES * 4);
    int*      cursor  = (int*)      alloc(N_NODES * 4);
    size_t zero_end = off;
    int*      row_ofs = (int*)      alloc((N_NODES + 16) * 4);
    float*    rs      = (float*)    alloc(N_NODES * 4);
    float*    acoef   = (float*)    alloc(N_NODES * 4);
    unsigned* bitmap  = (unsigned*) alloc((size_t)N_NODES * N_NODES / 8);  // 2 MB
    unsigned* uniq    = (unsigned*) alloc(N_EDGES * 4);
    uint2*    colcoef = (uint2*)    alloc(N_EDGES * 8);
    float*    W1T     = (float*)    alloc(DIN * DHID * 4);
    float*    WdT     = (float*)    alloc(DHID * DOUT * 4);
    float*    B       = (float*)    alloc(N_NODES * DHID * 4);
    float*    Y0      = (float*)    alloc(N_NODES * DHID * 4);
    float*    Y1      = (float*)    alloc(N_NODES * DHID * 4);
    float*    Y2      = (float*)    alloc(N_NODES * DHID * 4);
    float*    Y3      = (float*)    alloc(N_NODES * DHID * 4);
    float*    yD      = (float*)    alloc(N_NODES * DOUT * 4);
    float*    mcol    = (float*)    alloc(256 * 4);

    hipMemsetAsync(w, 0, zero_end, stream);
    hipMemsetAsync(bitmap, 0, (size_t)N_NODES * N_NODES / 8, stream);

    dedup_kernel<<<N_EDGES / 256, 256, 0, stream>>>(edge_index, bitmap, cnt, uniq, rowdeg, coldeg);
    scan_kernel<<<1, 1024, 0, stream>>>(rowdeg, coldeg, row_ofs, rs, acoef, a_param);
    fill_kernel<<<N_EDGES / 256, 256, 0, stream>>>(uniq, cnt, row_ofs, cursor, rs, colcoef);
    transpose_kernel<<<(2 * DIN * DHID + 255) / 256, 256, 0, stream>>>(W1, Wd, W1T, WdT);
    linear1_kernel<<<N_NODES, 128, 0, stream>>>(node_feat, W1T, b1, B);

    float* rot[3] = {Y0, Y1, Y2};
    const int NIT = 24;
    for (int phase = 0; phase < 2; ++phase) {
        const float* cur = (phase == 0) ? B : Y3;
        for (int k = 0; k < NIT; ++k) {
            float* dst = rot[k % 3];
            spmv_kernel<<<N_NODES / 2, 256, 0, stream>>>(cur, dst, B, colcoef, row_ofs, acoef);
            cur = dst;
        }
        float* last  = rot[(NIT - 1) % 3];
        float* prev  = rot[(NIT - 2) % 3];
        dots_kernel<<<512, 256, 0, stream>>>(last, prev, rot[(NIT - 3) % 3], acc + 1 + phase * 2);
        extrap_kernel<<<1024, 256, 0, stream>>>(last, prev, acc + 1 + phase * 2, Y3);
    }

    lineard_kernel<<<N_NODES, 192, 0, stream>>>(Y3, WdT, bd, yD);
    dim3 sg(N_NODES / TS, N_NODES / TS);
    simloss_kernel<<<sg, 256, 0, stream>>>(yD, acc);
    pool_kernel<<<DOUT, 256, 0, stream>>>(yD, mcol);
    final_kernel<<<1, 64, 0, stream>>>(mcol, W2, b2, acc, a_param, out);
}

// Round 3
// 347.770 us; speedup vs baseline: 2.7063x; 2.7063x over previous
//
#include <hip/hip_runtime.h>
#include <hip/hip_bf16.h>
#include <math.h>

#define N_NODES 4096
#define N_EDGES 131072
#define EPAD 8                         // CSR row padding (zero-coef ghost edges)
#define MAXE (N_EDGES + N_NODES * EPAD)
#define DIN 148
#define DHID 128
#define DOUT 148

// ---------------- dedup edges into bitmap + unique list + degrees ----------------
// NOTE: harness converts int64 inputs to int32 -> read as const int*.
__global__ __launch_bounds__(256) void dedup_kernel(const int* __restrict__ ei,
                                                    unsigned* __restrict__ bitmap,
                                                    unsigned* __restrict__ nuniq,
                                                    unsigned* __restrict__ uniq,
                                                    int* __restrict__ rowdeg,
                                                    int* __restrict__ coldeg) {
    int k = blockIdx.x * 256 + threadIdx.x;           // exactly N_EDGES threads
    int i = ei[k] & (N_NODES - 1);
    int j = ei[k + N_EDGES] & (N_NODES - 1);
    unsigned pos = (unsigned)i * (unsigned)N_NODES + (unsigned)j;
    unsigned w = pos >> 5, m = 1u << (pos & 31u);
    unsigned old = atomicOr(&bitmap[w], m);
    if (!(old & m)) {
        unsigned u = atomicAdd(nuniq, 1u);
        uniq[u] = ((unsigned)i << 12) | (unsigned)j;
        atomicAdd(&rowdeg[i], 1);
        atomicAdd(&coldeg[j], 1);
    }
}

// ---------------- prefix scan of PADDED row degrees + normalization coefs ----------------
__global__ __launch_bounds__(1024) void scan_kernel(const int* __restrict__ rowdeg,
                                                    const int* __restrict__ coldeg,
                                                    int* __restrict__ row_ofs,
                                                    float* __restrict__ rs,
                                                    float* __restrict__ acoef,
                                                    const float* __restrict__ a_param) {
    __shared__ int sh[1024];
    int t = threadIdx.x;
    int base = t * 4;
    int d0 = rowdeg[base], d1 = rowdeg[base+1], d2 = rowdeg[base+2], d3 = rowdeg[base+3];
    int v0 = (d0 + EPAD - 1) & ~(EPAD - 1);
    int v1 = (d1 + EPAD - 1) & ~(EPAD - 1);
    int v2 = (d2 + EPAD - 1) & ~(EPAD - 1);
    int v3 = (d3 + EPAD - 1) & ~(EPAD - 1);
    int p = v0 + v1 + v2 + v3;
    sh[t] = p;
    __syncthreads();
    for (int off = 1; off < 1024; off <<= 1) {
        int x = (t >= off) ? sh[t - off] : 0;
        __syncthreads();
        sh[t] += x;
        __syncthreads();
    }
    int excl = sh[t] - p;
    row_ofs[base]     = excl;
    row_ofs[base + 1] = excl + v0;
    row_ofs[base + 2] = excl + v0 + v1;
    row_ofs[base + 3] = excl + v0 + v1 + v2;
    if (t == 1023) row_ofs[N_NODES] = sh[1023];

    float alpha = 0.5f + 0.5f * tanhf(2.0f * a_param[0]);
    for (int r = 0; r < 4; ++r) {
        int i = base + r;
        int rd = rowdeg[i], cd = coldeg[i];
        rs[i]    = (rd > 0) ? rsqrtf((float)rd) : 0.0f;           // R_is[j] (row sums)
        acoef[i] = (cd > 0) ? alpha * rsqrtf((float)cd) : 0.0f;   // alpha * L_is[i] (col sums)
    }
}

// ---------------- fill CSR (col + per-edge coefficient); padded tail stays zero ----------------
__global__ __launch_bounds__(256) void fill_kernel(const unsigned* __restrict__ uniq,
                                                   const unsigned* __restrict__ nuniq,
                                                   const int* __restrict__ row_ofs,
                                                   int* __restrict__ cursor,
                                                   const float* __restrict__ rs,
                                                   uint2* __restrict__ colcoef) {
    int t = blockIdx.x * 256 + threadIdx.x;
    if (t >= (int)(*nuniq)) return;
    unsigned p = uniq[t];
    int i = (int)(p >> 12);
    int j = (int)(p & 4095u);
    int pos = atomicAdd(&cursor[i], 1);
    colcoef[row_ofs[i] + pos] = make_uint2((unsigned)j, __float_as_uint(rs[j]));
}

// ---------------- weight transposes for coalesced GEMV ----------------
__global__ __launch_bounds__(256) void transpose_kernel(const float* __restrict__ W1,
                                                        const float* __restrict__ Wd,
                                                        float* __restrict__ W1T,
                                                        float* __restrict__ WdT) {
    const int S = DIN * DHID; // 18944
    int id = blockIdx.x * 256 + threadIdx.x;
    if (id < S) {
        int k = id >> 7, d = id & 127;
        W1T[id] = W1[d * DIN + k];          // W1T[k*128 + d]
    } else if (id < 2 * S) {
        int id2 = id - S;
        int h = id2 / DOUT, o = id2 - h * DOUT;
        WdT[id2] = Wd[o * DHID + h];        // WdT[h*148 + o]
    }
}

// ---------------- linear1: B = node_feat @ W1.T + b1 ----------------
__global__ __launch_bounds__(128) void linear1_kernel(const float* __restrict__ nf,
                                                      const float* __restrict__ W1T,
                                                      const float* __restrict__ b1,
                                                      float* __restrict__ B) {
    __shared__ float s[DIN];
    int i = blockIdx.x, d = threadIdx.x;
    s[d] = nf[i * DIN + d];
    if (d + 128 < DIN) s[d + 128] = nf[i * DIN + d + 128];
    __syncthreads();
    float acc = b1[d];
    for (int k = 0; k < DIN; ++k) acc += s[k] * W1T[k * DHID + d];
    B[i * DHID + d] = acc;
}

// ---------------- one Richardson iteration, unroll-8 over padded edges ----------------
__global__ __launch_bounds__(256) void spmv_kernel(const float* __restrict__ xin,
                                                   float* __restrict__ xout,
                                                   const float* __restrict__ B,
                                                   const uint2* __restrict__ colcoef,
                                                   const int* __restrict__ row_ofs,
                                                   const float* __restrict__ acoef) {
    int r = blockIdx.x * 2 + (threadIdx.x >> 7);
    int d = threadIdx.x & 127;
    int s = row_ofs[r], e = row_ofs[r + 1];   // e - s is a multiple of 8
    float a0 = 0.0f, a1 = 0.0f;
    for (int t = s; t < e; t += 8) {
        const uint4* q = (const uint4*)(colcoef + t);   // 64B of edge data
        uint4 q0 = q[0], q1 = q[1], q2 = q[2], q3 = q[3];
        float x0 = xin[(int)q0.x * DHID + d];
        float x1 = xin[(int)q0.z * DHID + d];
        float x2 = xin[(int)q1.x * DHID + d];
        float x3 = xin[(int)q1.z * DHID + d];
        float x4 = xin[(int)q2.x * DHID + d];
        float x5 = xin[(int)q2.z * DHID + d];
        float x6 = xin[(int)q3.x * DHID + d];
        float x7 = xin[(int)q3.z * DHID + d];
        a0 += __uint_as_float(q0.y) * x0 + __uint_as_float(q1.y) * x2;
        a1 += __uint_as_float(q0.w) * x1 + __uint_as_float(q1.w) * x3;
        a0 += __uint_as_float(q2.y) * x4 + __uint_as_float(q3.y) * x6;
        a1 += __uint_as_float(q2.w) * x5 + __uint_as_float(q3.w) * x7;
    }
    int idx = r * DHID + d;
    xout[idx] = B[idx] + acoef[r] * (a0 + a1);
}

// ---------------- dots for extrapolation: out[0]+=dp.dp  out[1]+=dn.dp ----------------
__global__ __launch_bounds__(256) void dots_kernel(const float* __restrict__ last,
                                                   const float* __restrict__ prev,
                                                   const float* __restrict__ prev2,
                                                   double* __restrict__ out) {
    const int n = N_NODES * DHID;
    double s0 = 0.0, s1 = 0.0;
    for (int idx = blockIdx.x * 256 + threadIdx.x; idx < n; idx += gridDim.x * 256) {
        float dp = prev[idx] - prev2[idx];
        float dn = last[idx] - prev[idx];
        s0 += (double)dp * (double)dp;
        s1 += (double)dn * (double)dp;
    }
    __shared__ double sh0[256], sh1[256];
    int t = threadIdx.x;
    sh0[t] = s0; sh1[t] = s1;
    __syncthreads();
    for (int off = 128; off > 0; off >>= 1) {
        if (t < off) { sh0[t] += sh0[t + off]; sh1[t] += sh1[t + off]; }
        __syncthreads();
    }
    if (t == 0) {
        atomicAdd(&out[0], sh0[0]);
        atomicAdd(&out[1], sh1[0]);
    }
}

// ---------------- extrapolation: out = last + s*(last-prev), s = lam/(1-lam) ----------------
__global__ __launch_bounds__(256) void extrap_kernel(const float* __restrict__ last,
                                                     const float* __restrict__ prev,
                                                     const double* __restrict__ dots,
                                                     float* __restrict__ xo) {
    double d0 = dots[0], d1 = dots[1];
    float lam = (d0 > 0.0) ? (float)(d1 / d0) : 0.0f;
    float den = 1.0f - lam;
    if (fabsf(den) < 1e-4f) den = (den < 0.0f) ? -1e-4f : 1e-4f;
    float s = lam / den;
    s = fminf(fmaxf(s, -1e4f), 1e4f);
    const int n = N_NODES * DHID;
    for (int idx = blockIdx.x * 256 + threadIdx.x; idx < n; idx += gridDim.x * 256) {
        float l = last[idx];
        xo[idx] = l + s * (l - prev[idx]);
    }
}

// ---------------- linear_d: yD = x @ Wd.T + bd ----------------
__global__ __launch_bounds__(192) void lineard_kernel(const float* __restrict__ x,
                                                      const float* __restrict__ WdT,
                                                      const float* __restrict__ bd,
                                                      float* __restrict__ yD) {
    __shared__ float s[DHID];
    int i = blockIdx.x, o = threadIdx.x;
    if (o < DHID) s[o] = x[i * DHID + o];
    __syncthreads();
    if (o < DOUT) {
        float acc = bd[o];
        for (int h = 0; h < DHID; ++h) acc += s[h] * WdT[h * DOUT + o];
        yD[i * DOUT + o] = acc;
    }
}

// ---------------- sim loss: sum over i!=j of relu(yD_i . yD_j / sqrt(128)) ----------------
#define TS 64
#define KC 74
#define KSTR 77
__global__ __launch_bounds__(256) void simloss_kernel(const float* __restrict__ yD,
                                                      double* __restrict__ acc) {
    int bj = blockIdx.x, bi = blockIdx.y;
    if (bi > bj) return;
    __shared__ float As[TS][KSTR];
    __shared__ float Bs[TS][KSTR];
    int tid = threadIdx.x;
    int ty = tid >> 4, tx = tid & 15;
    float av[4][4];
#pragma unroll
    for (int r = 0; r < 4; ++r)
#pragma unroll
        for (int c = 0; c < 4; ++c) av[r][c] = 0.0f;

    for (int kc = 0; kc < 2; ++kc) {
        for (int idx = tid; idx < TS * KC; idx += 256) {
            int rr = idx / KC, cc = idx - rr * KC;
            As[rr][cc] = yD[(bi * TS + rr) * DOUT + kc * KC + cc];
            Bs[rr][cc] = yD[(bj * TS + rr) * DOUT + kc * KC + cc];
        }
        __syncthreads();
        for (int k = 0; k < KC; ++k) {
            float a0 = As[ty*4+0][k], a1 = As[ty*4+1][k], a2 = As[ty*4+2][k], a3 = As[ty*4+3][k];
            float b0 = Bs[tx*4+0][k], b1 = Bs[tx*4+1][k], b2 = Bs[tx*4+2][k], b3 = Bs[tx*4+3][k];
            av[0][0]+=a0*b0; av[0][1]+=a0*b1; av[0][2]+=a0*b2; av[0][3]+=a0*b3;
            av[1][0]+=a1*b0; av[1][1]+=a1*b1; av[1][2]+=a1*b2; av[1][3]+=a1*b3;
            av[2][0]+=a2*b0; av[2][1]+=a2*b1; av[2][2]+=a2*b2; av[2][3]+=a2*b3;
            av[3][0]+=a3*b0; av[3][1]+=a3*b1; av[3][2]+=a3*b2; av[3][3]+=a3*b3;
        }
        __syncthreads();
    }
    const float inv = 0.0883883476483184405f; // 1/sqrt(128)
    float wgt = (bi == bj) ? 1.0f : 2.0f;
    float lsum = 0.0f;
#pragma unroll
    for (int r = 0; r < 4; ++r)
#pragma unroll
        for (int c = 0; c < 4; ++c) {
            int gi = bi * TS + ty * 4 + r;
            int gj = bj * TS + tx * 4 + c;
            float v = av[r][c] * inv;
            if (gi != gj && v > 0.0f) lsum += wgt * v;
        }
    for (int o2 = 32; o2 > 0; o2 >>= 1) lsum += __shfl_down(lsum, o2);
    __shared__ float wsum[4];
    if ((tid & 63) == 0) wsum[tid >> 6] = lsum;
    __syncthreads();
    if (tid == 0) atomicAdd(acc, (double)(wsum[0] + wsum[1] + wsum[2] + wsum[3]));
}

// ---------------- column max over nodes ----------------
__global__ __launch_bounds__(256) void pool_kernel(const float* __restrict__ yD,
                                                   float* __restrict__ m) {
    int o = blockIdx.x;
    int tid = threadIdx.x;
    float mx = -3.4e38f;
    for (int i = tid; i < N_NODES; i += 256) mx = fmaxf(mx, yD[i * DOUT + o]);
    for (int off = 32; off > 0; off >>= 1) mx = fmaxf(mx, __shfl_down(mx, off));
    __shared__ float sm[4];
    if ((tid & 63) == 0) sm[tid >> 6] = mx;
    __syncthreads();
    if (tid == 0) m[o] = fmaxf(fmaxf(sm[0], sm[1]), fmaxf(sm[2], sm[3]));
}

// ---------------- final outputs ----------------
__global__ __launch_bounds__(64) void final_kernel(const float* __restrict__ m,
                                                   const float* __restrict__ W2,
                                                   const float* __restrict__ b2,
                                                   const double* __restrict__ acc,
                                                   const float* __restrict__ a_param,
                                                   float* __restrict__ out) {
    int l = threadIdx.x;
    float alpha = 0.5f + 0.5f * tanhf(2.0f * a_param[0]);
    float oma = 1.0f - alpha;
    float s0 = 0.0f, s1 = 0.0f;
    for (int o = l; o < DOUT; o += 64) {
        float p = fmaxf(m[o], 0.0f);
        s0 += p * W2[o];
        s1 += p * W2[DOUT + o];
    }
    for (int off = 32; off > 0; off >>= 1) {
        s0 += __shfl_down(s0, off);
        s1 += __shfl_down(s1, off);
    }
    if (l == 0) {
        out[0] = b2[0] + oma * s0;
        out[1] = b2[1] + oma * s1;
        out[2] = (float)(acc[0] / (4096.0 * 4095.0));
    }
}

extern "C" void kernel_launch(void* const* d_in, const int* in_sizes, int n_in,
                              void* d_out, int out_size, void* d_ws, size_t ws_size,
                              hipStream_t stream) {
    (void)in_sizes; (void)n_in; (void)out_size; (void)ws_size;
    const float* node_feat  = (const float*)d_in[0];
    const int*   edge_index = (const int*)d_in[1];   // harness converts int64 -> int32
    const float* W1         = (const float*)d_in[3];
    const float* b1         = (const float*)d_in[4];
    const float* a_param    = (const float*)d_in[5];
    const float* Wd         = (const float*)d_in[6];
    const float* bd         = (const float*)d_in[7];
    const float* W2         = (const float*)d_in[8];
    const float* b2         = (const float*)d_in[9];
    float*       out        = (float*)d_out;

    char* w = (char*)d_ws;
    size_t off = 0;
    auto alloc = [&](size_t bytes) -> char* {
        char* p = w + off;
        off = (off + bytes + 255) & ~(size_t)255;
        return p;
    };
    double*   acc     = (double*)   alloc(8 * sizeof(double));   // [0]=loss, [1,2]=dots
    unsigned* cnt     = (unsigned*) alloc(16 * sizeof(unsigned));
    int*      rowdeg  = (int*)      alloc(N_NODES * 4);
    int*      coldeg  = (int*)      alloc(N_NODES * 4);
    int*      cursor  = (int*)      alloc(N_NODES * 4);
    size_t zero_end = off;
    int*      row_ofs = (int*)      alloc((N_NODES + 16) * 4);
    float*    rs      = (float*)    alloc(N_NODES * 4);
    float*    acoef   = (float*)    alloc(N_NODES * 4);
    unsigned* bitmap  = (unsigned*) alloc((size_t)N_NODES * N_NODES / 8);  // 2 MB
    unsigned* uniq    = (unsigned*) alloc(N_EDGES * 4);
    uint2*    colcoef = (uint2*)    alloc((size_t)MAXE * 8);               // padded CSR
    float*    W1T     = (float*)    alloc(DIN * DHID * 4);
    float*    WdT     = (float*)    alloc(DHID * DOUT * 4);
    float*    B       = (float*)    alloc(N_NODES * DHID * 4);
    float*    Y0      = (float*)    alloc(N_NODES * DHID * 4);
    float*    Y1      = (float*)    alloc(N_NODES * DHID * 4);
    float*    Y2      = (float*)    alloc(N_NODES * DHID * 4);
    float*    Y3      = (float*)    alloc(N_NODES * DHID * 4);
    float*    yD      = (float*)    alloc(N_NODES * DOUT * 4);
    float*    mcol    = (float*)    alloc(256 * 4);

    hipMemsetAsync(w, 0, zero_end, stream);
    hipMemsetAsync(bitmap, 0, (size_t)N_NODES * N_NODES / 8, stream);
    hipMemsetAsync(colcoef, 0, (size_t)MAXE * 8, stream);

    dedup_kernel<<<N_EDGES / 256, 256, 0, stream>>>(edge_index, bitmap, cnt, uniq, rowdeg, coldeg);
    scan_kernel<<<1, 1024, 0, stream>>>(rowdeg, coldeg, row_ofs, rs, acoef, a_param);
    fill_kernel<<<N_EDGES / 256, 256, 0, stream>>>(uniq, cnt, row_ofs, cursor, rs, colcoef);
    transpose_kernel<<<(2 * DIN * DHID + 255) / 256, 256, 0, stream>>>(W1, Wd, W1T, WdT);
    linear1_kernel<<<N_NODES, 128, 0, stream>>>(node_feat, W1T, b1, B);

    // single Richardson phase + Perron extrapolation
    float* rot[3] = {Y0, Y1, Y2};
    const int NIT = 14;
    const float* cur = B;
    for (int k = 0; k < NIT; ++k) {
        float* dst = rot[k % 3];
        spmv_kernel<<<N_NODES / 2, 256, 0, stream>>>(cur, dst, B, colcoef, row_ofs, acoef);
        cur = dst;
    }
    float* last = rot[(NIT - 1) % 3];
    float* prev = rot[(NIT - 2) % 3];
    dots_kernel<<<512, 256, 0, stream>>>(last, prev, rot[(NIT - 3) % 3], acc + 1);
    extrap_kernel<<<1024, 256, 0, stream>>>(last, prev, acc + 1, Y3);

    lineard_kernel<<<N_NODES, 192, 0, stream>>>(Y3, WdT, bd, yD);
    dim3 sg(N_NODES / TS, N_NODES / TS);
    simloss_kernel<<<sg, 256, 0, stream>>>(yD, acc);
    pool_kernel<<<DOUT, 256, 0, stream>>>(yD, mcol);
    final_kernel<<<1, 64, 0, stream>>>(mcol, W2, b2, acc, a_param, out);
}

// Round 4
// 250.736 us; speedup vs baseline: 3.7537x; 1.3870x over previous
//
#include <hip/hip_runtime.h>
#include <hip/hip_bf16.h>
#include <math.h>

#define N_NODES 4096
#define N_EDGES 131072
#define EPAD 8                         // CSR row padding (zero-coef ghost edges)
#define MAXE (N_EDGES + N_NODES * EPAD)
#define DIN 148
#define DHID 128
#define DOUT 148
#define KP 160                         // padded K for f16 MFMA simloss
#define LSTR 168                       // LDS row stride in halves (336B, 16B-aligned, 2-way banks = free)

typedef __attribute__((ext_vector_type(8))) _Float16 half8;
typedef __attribute__((ext_vector_type(4))) float f32x4;

// ---------------- dedup edges into bitmap + unique list + degrees ----------------
// NOTE: harness converts int64 inputs to int32 -> read as const int*.
__global__ __launch_bounds__(256) void dedup_kernel(const int* __restrict__ ei,
                                                    unsigned* __restrict__ bitmap,
                                                    unsigned* __restrict__ nuniq,
                                                    unsigned* __restrict__ uniq,
                                                    int* __restrict__ rowdeg,
                                                    int* __restrict__ coldeg) {
    int k = blockIdx.x * 256 + threadIdx.x;           // exactly N_EDGES threads
    int i = ei[k] & (N_NODES - 1);
    int j = ei[k + N_EDGES] & (N_NODES - 1);
    unsigned pos = (unsigned)i * (unsigned)N_NODES + (unsigned)j;
    unsigned w = pos >> 5, m = 1u << (pos & 31u);
    unsigned old = atomicOr(&bitmap[w], m);
    if (!(old & m)) {
        unsigned u = atomicAdd(nuniq, 1u);
        uniq[u] = ((unsigned)i << 12) | (unsigned)j;
        atomicAdd(&rowdeg[i], 1);
        atomicAdd(&coldeg[j], 1);
    }
}

// ---------------- prefix scan of PADDED row degrees + normalization coefs ----------------
__global__ __launch_bounds__(1024) void scan_kernel(const int* __restrict__ rowdeg,
                                                    const int* __restrict__ coldeg,
                                                    int* __restrict__ row_ofs,
                                                    float* __restrict__ rs,
                                                    float* __restrict__ acoef,
                                                    const float* __restrict__ a_param) {
    __shared__ int sh[1024];
    int t = threadIdx.x;
    int base = t * 4;
    int d0 = rowdeg[base], d1 = rowdeg[base+1], d2 = rowdeg[base+2], d3 = rowdeg[base+3];
    int v0 = (d0 + EPAD - 1) & ~(EPAD - 1);
    int v1 = (d1 + EPAD - 1) & ~(EPAD - 1);
    int v2 = (d2 + EPAD - 1) & ~(EPAD - 1);
    int v3 = (d3 + EPAD - 1) & ~(EPAD - 1);
    int p = v0 + v1 + v2 + v3;
    sh[t] = p;
    __syncthreads();
    for (int off = 1; off < 1024; off <<= 1) {
        int x = (t >= off) ? sh[t - off] : 0;
        __syncthreads();
        sh[t] += x;
        __syncthreads();
    }
    int excl = sh[t] - p;
    row_ofs[base]     = excl;
    row_ofs[base + 1] = excl + v0;
    row_ofs[base + 2] = excl + v0 + v1;
    row_ofs[base + 3] = excl + v0 + v1 + v2;
    if (t == 1023) row_ofs[N_NODES] = sh[1023];

    float alpha = 0.5f + 0.5f * tanhf(2.0f * a_param[0]);
    for (int r = 0; r < 4; ++r) {
        int i = base + r;
        int rd = rowdeg[i], cd = coldeg[i];
        rs[i]    = (rd > 0) ? rsqrtf((float)rd) : 0.0f;           // R_is[j] (row sums)
        acoef[i] = (cd > 0) ? alpha * rsqrtf((float)cd) : 0.0f;   // alpha * L_is[i] (col sums)
    }
}

// ---------------- fill CSR (col + per-edge coefficient); padded tail stays zero ----------------
__global__ __launch_bounds__(256) void fill_kernel(const unsigned* __restrict__ uniq,
                                                   const unsigned* __restrict__ nuniq,
                                                   const int* __restrict__ row_ofs,
                                                   int* __restrict__ cursor,
                                                   const float* __restrict__ rs,
                                                   uint2* __restrict__ colcoef) {
    int t = blockIdx.x * 256 + threadIdx.x;
    if (t >= (int)(*nuniq)) return;
    unsigned p = uniq[t];
    int i = (int)(p >> 12);
    int j = (int)(p & 4095u);
    int pos = atomicAdd(&cursor[i], 1);
    colcoef[row_ofs[i] + pos] = make_uint2((unsigned)j, __float_as_uint(rs[j]));
}

// ---------------- weight transposes for coalesced GEMV ----------------
__global__ __launch_bounds__(256) void transpose_kernel(const float* __restrict__ W1,
                                                        const float* __restrict__ Wd,
                                                        float* __restrict__ W1T,
                                                        float* __restrict__ WdT) {
    const int S = DIN * DHID; // 18944
    int id = blockIdx.x * 256 + threadIdx.x;
    if (id < S) {
        int k = id >> 7, d = id & 127;
        W1T[id] = W1[d * DIN + k];          // W1T[k*128 + d]
    } else if (id < 2 * S) {
        int id2 = id - S;
        int h = id2 / DOUT, o = id2 - h * DOUT;
        WdT[id2] = Wd[o * DHID + h];        // WdT[h*148 + o]
    }
}

// ---------------- linear1: B = node_feat @ W1.T + b1 ----------------
__global__ __launch_bounds__(128) void linear1_kernel(const float* __restrict__ nf,
                                                      const float* __restrict__ W1T,
                                                      const float* __restrict__ b1,
                                                      float* __restrict__ B) {
    __shared__ float s[DIN];
    int i = blockIdx.x, d = threadIdx.x;
    s[d] = nf[i * DIN + d];
    if (d + 128 < DIN) s[d + 128] = nf[i * DIN + d + 128];
    __syncthreads();
    float acc = b1[d];
    for (int k = 0; k < DIN; ++k) acc += s[k] * W1T[k * DHID + d];
    B[i * DHID + d] = acc;
}

// ---------------- Richardson iteration: wave-per-row, float2 lanes, scalar edge loads ----------------
__global__ __launch_bounds__(256) void spmv_kernel(const float* __restrict__ xin,
                                                   float* __restrict__ xout,
                                                   const float* __restrict__ B,
                                                   const uint2* __restrict__ colcoef,
                                                   const int* __restrict__ row_ofs,
                                                   const float* __restrict__ acoef) {
    int wid = __builtin_amdgcn_readfirstlane((int)(threadIdx.x >> 6));  // wave id 0..3 (SGPR)
    int lane = threadIdx.x & 63;
    int r = blockIdx.x * 4 + wid;
    int s = row_ofs[r], e = row_ofs[r + 1];       // wave-uniform -> scalar loads
    const float2* __restrict__ x2 = (const float2*)xin;
    float ax = 0.0f, ay = 0.0f;
    for (int t = s; t < e; t += 8) {              // e-s is a multiple of 8
        uint2 e0 = colcoef[t+0], e1 = colcoef[t+1], e2 = colcoef[t+2], e3 = colcoef[t+3];
        uint2 e4 = colcoef[t+4], e5 = colcoef[t+5], e6 = colcoef[t+6], e7 = colcoef[t+7];
        float2 x0 = x2[(int)e0.x * 64 + lane];
        float2 x1 = x2[(int)e1.x * 64 + lane];
        float2 x3v = x2[(int)e3.x * 64 + lane];
        float2 x2v = x2[(int)e2.x * 64 + lane];
        float2 x4 = x2[(int)e4.x * 64 + lane];
        float2 x5 = x2[(int)e5.x * 64 + lane];
        float2 x6 = x2[(int)e6.x * 64 + lane];
        float2 x7 = x2[(int)e7.x * 64 + lane];
        float c0 = __uint_as_float(e0.y), c1 = __uint_as_float(e1.y);
        float c2 = __uint_as_float(e2.y), c3 = __uint_as_float(e3.y);
        float c4 = __uint_as_float(e4.y), c5 = __uint_as_float(e5.y);
        float c6 = __uint_as_float(e6.y), c7 = __uint_as_float(e7.y);
        ax += c0 * x0.x + c1 * x1.x + c2 * x2v.x + c3 * x3v.x;
        ay += c0 * x0.y + c1 * x1.y + c2 * x2v.y + c3 * x3v.y;
        ax += c4 * x4.x + c5 * x5.x + c6 * x6.x + c7 * x7.x;
        ay += c4 * x4.y + c5 * x5.y + c6 * x6.y + c7 * x7.y;
    }
    float ac = acoef[r];
    int idx = r * 64 + lane;
    float2 b = ((const float2*)B)[idx];
    ((float2*)xout)[idx] = make_float2(b.x + ac * ax, b.y + ac * ay);
}

// ---------------- dots for extrapolation: out[0]+=dp.dp  out[1]+=dn.dp ----------------
__global__ __launch_bounds__(256) void dots_kernel(const float* __restrict__ last,
                                                   const float* __restrict__ prev,
                                                   const float* __restrict__ prev2,
                                                   double* __restrict__ out) {
    const int n = N_NODES * DHID;
    double s0 = 0.0, s1 = 0.0;
    for (int idx = blockIdx.x * 256 + threadIdx.x; idx < n; idx += gridDim.x * 256) {
        float dp = prev[idx] - prev2[idx];
        float dn = last[idx] - prev[idx];
        s0 += (double)dp * (double)dp;
        s1 += (double)dn * (double)dp;
    }
    __shared__ double sh0[256], sh1[256];
    int t = threadIdx.x;
    sh0[t] = s0; sh1[t] = s1;
    __syncthreads();
    for (int off = 128; off > 0; off >>= 1) {
        if (t < off) { sh0[t] += sh0[t + off]; sh1[t] += sh1[t + off]; }
        __syncthreads();
    }
    if (t == 0) {
        atomicAdd(&out[0], sh0[0]);
        atomicAdd(&out[1], sh1[0]);
    }
}

// ---------------- extrapolation: out = last + s*(last-prev), s = lam/(1-lam) ----------------
__global__ __launch_bounds__(256) void extrap_kernel(const float* __restrict__ last,
                                                     const float* __restrict__ prev,
                                                     const double* __restrict__ dots,
                                                     float* __restrict__ xo) {
    double d0 = dots[0], d1 = dots[1];
    float lam = (d0 > 0.0) ? (float)(d1 / d0) : 0.0f;
    float den = 1.0f - lam;
    if (fabsf(den) < 1e-4f) den = (den < 0.0f) ? -1e-4f : 1e-4f;
    float s = lam / den;
    s = fminf(fmaxf(s, -1e4f), 1e4f);
    const int n = N_NODES * DHID;
    for (int idx = blockIdx.x * 256 + threadIdx.x; idx < n; idx += gridDim.x * 256) {
        float l = last[idx];
        xo[idx] = l + s * (l - prev[idx]);
    }
}

// ---------------- linear_d: yD = x @ Wd.T + bd ----------------
__global__ __launch_bounds__(192) void lineard_kernel(const float* __restrict__ x,
                                                      const float* __restrict__ WdT,
                                                      const float* __restrict__ bd,
                                                      float* __restrict__ yD) {
    __shared__ float s[DHID];
    int i = blockIdx.x, o = threadIdx.x;
    if (o < DHID) s[o] = x[i * DHID + o];
    __syncthreads();
    if (o < DOUT) {
        float acc = bd[o];
        for (int h = 0; h < DHID; ++h) acc += s[h] * WdT[h * DOUT + o];
        yD[i * DOUT + o] = acc;
    }
}

// ---------------- convert yD (fp32, K=148) -> f16 padded [4096][KP] ----------------
__global__ __launch_bounds__(256) void convert_kernel(const float* __restrict__ yD,
                                                      _Float16* __restrict__ yH) {
    int idx = blockIdx.x * 256 + threadIdx.x;     // 4096*KP threads
    int row = idx / KP, col = idx - row * KP;
    yH[idx] = (col < DOUT) ? (_Float16)yD[row * DOUT + col] : (_Float16)0.0f;
}

// ---------------- sim loss via f16 MFMA: sum over i!=j of relu(yD_i.yD_j/sqrt(128)) ----------------
__global__ __launch_bounds__(256) void simloss_kernel(const _Float16* __restrict__ yH,
                                                      double* __restrict__ acc) {
    // linear block -> upper-triangle tile (ti <= tj), 32x32 tiles of 128
    int b = blockIdx.x;
    int ti = 0, rem = b;
    while (rem >= 32 - ti) { rem -= 32 - ti; ++ti; }
    int tj = ti + rem;

    __shared__ alignas(16) _Float16 As[128 * LSTR];
    __shared__ alignas(16) _Float16 Bs[128 * LSTR];
    int tid = threadIdx.x;

    // stage tiles: 128 rows x KP halves, half8 chunks (KP/8 = 20 per row)
    const half8* __restrict__ src = (const half8*)yH;   // row stride = KP/8 = 20
    for (int v = tid; v < 128 * (KP / 8); v += 256) {
        int rr = v / (KP / 8), cc = v - rr * (KP / 8);
        *(half8*)(&As[rr * LSTR + cc * 8]) = src[(ti * 128 + rr) * (KP / 8) + cc];
        *(half8*)(&Bs[rr * LSTR + cc * 8]) = src[(tj * 128 + rr) * (KP / 8) + cc];
    }
    __syncthreads();

    int wid = tid >> 6, lane = tid & 63;
    int wr = wid >> 1, wc = wid & 1;              // wave -> 64x64 subtile
    int fr = lane & 15, k0 = (lane >> 4) * 8;

    f32x4 C[4][4];
#pragma unroll
    for (int m = 0; m < 4; ++m)
#pragma unroll
        for (int n = 0; n < 4; ++n) C[m][n] = (f32x4)0.0f;

#pragma unroll
    for (int kk = 0; kk < KP / 32; ++kk) {
        half8 a[4], bf[4];
#pragma unroll
        for (int m = 0; m < 4; ++m)
            a[m] = *(const half8*)(&As[(wr * 64 + m * 16 + fr) * LSTR + kk * 32 + k0]);
#pragma unroll
        for (int n = 0; n < 4; ++n)
            bf[n] = *(const half8*)(&Bs[(wc * 64 + n * 16 + fr) * LSTR + kk * 32 + k0]);
#pragma unroll
        for (int m = 0; m < 4; ++m)
#pragma unroll
            for (int n = 0; n < 4; ++n)
                C[m][n] = __builtin_amdgcn_mfma_f32_16x16x32_f16(a[m], bf[n], C[m][n], 0, 0, 0);
    }

    const float inv = 0.0883883476483184405f;     // 1/sqrt(128)
    float wgt = (ti == tj) ? 1.0f : 2.0f;
    float lsum = 0.0f;
    int rq = (lane >> 4) * 4;
#pragma unroll
    for (int m = 0; m < 4; ++m)
#pragma unroll
        for (int n = 0; n < 4; ++n)
#pragma unroll
            for (int reg = 0; reg < 4; ++reg) {
                int gi = ti * 128 + wr * 64 + m * 16 + rq + reg;
                int gj = tj * 128 + wc * 64 + n * 16 + fr;
                float v = C[m][n][reg] * inv;
                if (gi != gj && v > 0.0f) lsum += wgt * v;
            }
    for (int o2 = 32; o2 > 0; o2 >>= 1) lsum += __shfl_down(lsum, o2);
    __shared__ float wsum[4];
    if ((tid & 63) == 0) wsum[tid >> 6] = lsum;
    __syncthreads();
    if (tid == 0) atomicAdd(acc, (double)(wsum[0] + wsum[1] + wsum[2] + wsum[3]));
}

// ---------------- column max over nodes ----------------
__global__ __launch_bounds__(256) void pool_kernel(const float* __restrict__ yD,
                                                   float* __restrict__ m) {
    int o = blockIdx.x;
    int tid = threadIdx.x;
    float mx = -3.4e38f;
    for (int i = tid; i < N_NODES; i += 256) mx = fmaxf(mx, yD[i * DOUT + o]);
    for (int off = 32; off > 0; off >>= 1) mx = fmaxf(mx, __shfl_down(mx, off));
    __shared__ float sm[4];
    if ((tid & 63) == 0) sm[tid >> 6] = mx;
    __syncthreads();
    if (tid == 0) m[o] = fmaxf(fmaxf(sm[0], sm[1]), fmaxf(sm[2], sm[3]));
}

// ---------------- final outputs ----------------
__global__ __launch_bounds__(64) void final_kernel(const float* __restrict__ m,
                                                   const float* __restrict__ W2,
                                                   const float* __restrict__ b2,
                                                   const double* __restrict__ acc,
                                                   const float* __restrict__ a_param,
                                                   float* __restrict__ out) {
    int l = threadIdx.x;
    float alpha = 0.5f + 0.5f * tanhf(2.0f * a_param[0]);
    float oma = 1.0f - alpha;
    float s0 = 0.0f, s1 = 0.0f;
    for (int o = l; o < DOUT; o += 64) {
        float p = fmaxf(m[o], 0.0f);
        s0 += p * W2[o];
        s1 += p * W2[DOUT + o];
    }
    for (int off = 32; off > 0; off >>= 1) {
        s0 += __shfl_down(s0, off);
        s1 += __shfl_down(s1, off);
    }
    if (l == 0) {
        out[0] = b2[0] + oma * s0;
        out[1] = b2[1] + oma * s1;
        out[2] = (float)(acc[0] / (4096.0 * 4095.0));
    }
}

extern "C" void kernel_launch(void* const* d_in, const int* in_sizes, int n_in,
                              void* d_out, int out_size, void* d_ws, size_t ws_size,
                              hipStream_t stream) {
    (void)in_sizes; (void)n_in; (void)out_size; (void)ws_size;
    const float* node_feat  = (const float*)d_in[0];
    const int*   edge_index = (const int*)d_in[1];   // harness converts int64 -> int32
    const float* W1         = (const float*)d_in[3];
    const float* b1         = (const float*)d_in[4];
    const float* a_param    = (const float*)d_in[5];
    const float* Wd         = (const float*)d_in[6];
    const float* bd         = (const float*)d_in[7];
    const float* W2         = (const float*)d_in[8];
    const float* b2         = (const float*)d_in[9];
    float*       out        = (float*)d_out;

    char* w = (char*)d_ws;
    size_t off = 0;
    auto alloc = [&](size_t bytes) -> char* {
        char* p = w + off;
        off = (off + bytes + 255) & ~(size_t)255;
        return p;
    };
    double*   acc     = (double*)   alloc(8 * sizeof(double));   // [0]=loss, [1,2]=dots
    unsigned* cnt     = (unsigned*) alloc(16 * sizeof(unsigned));
    int*      rowdeg  = (int*)      alloc(N_NODES * 4);
    int*      coldeg  = (int*)      alloc(N_NODES * 4);
    int*      cursor  = (int*)      alloc(N_NODES * 4);
    size_t zero_end = off;
    int*      row_ofs = (int*)      alloc((N_NODES + 16) * 4);
    float*    rs      = (float*)    alloc(N_NODES * 4);
    float*    acoef   = (float*)    alloc(N_NODES * 4);
    unsigned* bitmap  = (unsigned*) alloc((size_t)N_NODES * N_NODES / 8);  // 2 MB
    unsigned* uniq    = (unsigned*) alloc(N_EDGES * 4);
    uint2*    colcoef = (uint2*)    alloc((size_t)MAXE * 8);               // padded CSR
    float*    W1T     = (float*)    alloc(DIN * DHID * 4);
    float*    WdT     = (float*)    alloc(DHID * DOUT * 4);
    float*    B       = (float*)    alloc(N_NODES * DHID * 4);
    float*    Y0      = (float*)    alloc(N_NODES * DHID * 4);
    float*    Y1      = (float*)    alloc(N_NODES * DHID * 4);
    float*    Y2      = (float*)    alloc(N_NODES * DHID * 4);
    float*    Y3      = (float*)    alloc(N_NODES * DHID * 4);
    float*    yD      = (float*)    alloc(N_NODES * DOUT * 4);
    _Float16* yH      = (_Float16*) alloc((size_t)N_NODES * KP * 2);
    float*    mcol    = (float*)    alloc(256 * 4);

    hipMemsetAsync(w, 0, zero_end, stream);
    hipMemsetAsync(bitmap, 0, (size_t)N_NODES * N_NODES / 8, stream);
    hipMemsetAsync(colcoef, 0, (size_t)MAXE * 8, stream);

    dedup_kernel<<<N_EDGES / 256, 256, 0, stream>>>(edge_index, bitmap, cnt, uniq, rowdeg, coldeg);
    scan_kernel<<<1, 1024, 0, stream>>>(rowdeg, coldeg, row_ofs, rs, acoef, a_param);
    fill_kernel<<<N_EDGES / 256, 256, 0, stream>>>(uniq, cnt, row_ofs, cursor, rs, colcoef);
    transpose_kernel<<<(2 * DIN * DHID + 255) / 256, 256, 0, stream>>>(W1, Wd, W1T, WdT);
    linear1_kernel<<<N_NODES, 128, 0, stream>>>(node_feat, W1T, b1, B);

    // single Richardson phase + Perron extrapolation
    float* rot[3] = {Y0, Y1, Y2};
    const int NIT = 14;
    const float* cur = B;
    for (int k = 0; k < NIT; ++k) {
        float* dst = rot[k % 3];
        spmv_kernel<<<N_NODES / 4, 256, 0, stream>>>(cur, dst, B, colcoef, row_ofs, acoef);
        cur = dst;
    }
    float* last = rot[(NIT - 1) % 3];
    float* prev = rot[(NIT - 2) % 3];
    dots_kernel<<<512, 256, 0, stream>>>(last, prev, rot[(NIT - 3) % 3], acc + 1);
    extrap_kernel<<<1024, 256, 0, stream>>>(last, prev, acc + 1, Y3);

    lineard_kernel<<<N_NODES, 192, 0, stream>>>(Y3, WdT, bd, yD);
    convert_kernel<<<(N_NODES * KP) / 256, 256, 0, stream>>>(yD, yH);
    simloss_kernel<<<(32 * 33) / 2, 256, 0, stream>>>(yH, acc);
    pool_kernel<<<DOUT, 256, 0, stream>>>(yD, mcol);
    final_kernel<<<1, 64, 0, stream>>>(mcol, W2, b2, acc, a_param, out);
}